// Round 13
// baseline (102.902 us; speedup 1.0000x reference)
//
#include <hip/hip_runtime.h>
#include <cstdint>
#include <cstddef>

// Problem constants (match reference file)
#define BB 4
#define MM 8192
#define NN 6890
#define NSEG 64
#define SEGN 108          // ceil(6890/64); last segment has 86
#define G 16              // tournament group size
#define GMAX 7            // max groups per segment
#define GSTRIDE 17        // group stride in float4 slots
#define CHUNKS 4          // MM / MQ
#define MQ 2048           // queries per nn block (TPB * QT)
#define QT 8              // queries per thread (8 independent chains)
#define TPB 256
#define NQ (BB * MM)      // 32768 queries
#define NFBLK 512         // finalize blocks (seg-split)

static constexpr float MIN_T2 = 0.005f * 0.005f;   // MIN_DIST_THRESH^2

// ws layout (bytes):
//   [0, 16777216)            u64 partials[NSEG][NQ]
//       key = emap(e)<<32 | seg<<15 | loc<<8 | flag<<7
//   [16777216, +2048)        float bsum[512]
//   [16779264, +2048)        int   bmatch[512]
#define OFF_BSUM   16777216
#define OFF_BMATCH (16777216 + 2048)

static __device__ __forceinline__ unsigned long long u64min(
    unsigned long long a, unsigned long long b) { return a < b ? a : b; }

// Shared helpers: IDENTICAL expressions in nn (scan) and finalize
// (recovery) so recomputed e is bit-exact.
static __device__ __forceinline__ float4 prep_cand(
    const float* __restrict__ vtb, const int* __restrict__ validb, int n)
{
    const float* p = vtb + (size_t)n * 3;
    float x = p[0], y = p[1], z = p[2];
    float s2 = x * x + y * y + z * z;
    if (validb[n] <= 0) s2 = __builtin_inff();
    return make_float4(-2.0f * x, -2.0f * y, -2.0f * z, s2);
}
static __device__ __forceinline__ float edot(float4 c, float qx, float qy,
                                             float qz)
{
    return fmaf(c.x, qx, fmaf(c.y, qy, fmaf(c.z, qz, c.w)));
}
// order-preserving float->u32 (monotone over all floats incl. negatives)
static __device__ __forceinline__ unsigned emap(float e) {
    unsigned b = __float_as_uint(e);
    return ((int)b < 0) ? ~b : (b | 0x80000000u);
}

// Kernel 1: per-(batch, m-chunk, n-segment) NN, group tournament,
// deferred index recovery (R12-verified, absmax 0.0).
// R12 post-mortem: LDS pipe still binding -- 32 waves/CU x 112
// ds_read_b128 x 12cy = 18us/CU vs VALU 10us/SIMD. LDS total scales with
// WAVE COUNT (every wave broadcast-reads all candidates), so R13: QT=8 /
// CHUNKS=4 halves waves (8192->4096) -> LDS 9us/CU, VALU unchanged 10us.
// Pipes balanced. TLP drops 8->4 waves/SIMD but per-wave ILP doubles
// (8 chains); 1024 blocks = 4 blocks/CU keeps balance fine. R5 precedent:
// this QT=8 shape compiles to 52 VGPR, no spill (no bounds-pinning, no
// forced unroll -- the R6/R10 failure modes).
__global__ __launch_bounds__(TPB) void nn_kernel(
    const float* __restrict__ cloth, const float* __restrict__ vt,
    const int* __restrict__ valid, unsigned long long* __restrict__ partials)
{
    __shared__ float4 lds[GMAX * GSTRIDE];   // 119 float4 = 1904 B
    int bid   = blockIdx.x;            // 1024 blocks = 4/CU
    int seg   = bid & (NSEG - 1);
    int chunk = (bid >> 6) & (CHUNKS - 1);
    int b     = bid >> 8;
    int n0    = seg * SEGN;
    int segn  = (NN - n0 < SEGN) ? (NN - n0) : SEGN;
    int ngroups = (segn + G - 1) / G;
    int npad    = ngroups * G;

    const float* vtb    = vt + (size_t)b * NN * 3;
    const int*   validb = valid + b * NN;

    // fused candidate prep (shared helper); pads (0,0,0,+inf) inert
    if (threadIdx.x < npad) {
        float4 v = make_float4(0.0f, 0.0f, 0.0f, __builtin_inff());
        if (threadIdx.x < segn) v = prep_cand(vtb, validb, n0 + threadIdx.x);
        int slot = (threadIdx.x >> 4) * GSTRIDE + (threadIdx.x & (G - 1));
        lds[slot] = v;
    }

    float qx[QT], qy[QT], qz[QT], qc2[QT], bd[QT];
    int gb[QT];
    int m0 = chunk * MQ + threadIdx.x;
#pragma unroll
    for (int j = 0; j < QT; j++) {
        int m = m0 + j * TPB;
        const float* p = cloth + ((size_t)b * MM + m) * 3;
        float x = p[0], y = p[1], z = p[2];
        qx[j] = x; qy[j] = y; qz[j] = z;
        qc2[j] = x * x + y * y + z * z;
        bd[j] = __builtin_inff();
        gb[j] = 0;
    }
    __syncthreads();

    // Hot loop: UNFILTERED value-min in shifted space e = s2 - 2 c.s,
    // group tournament, candidates in pairs -> min3 fold.
    for (int g = 0; g < ngroups; g++) {
        int base = g * GSTRIDE;
        float gm[QT];
#pragma unroll
        for (int j = 0; j < QT; j++) gm[j] = __builtin_inff();
#pragma unroll
        for (int t = 0; t < G; t += 2) {
            float4 c0 = lds[base + t];
            float4 c1 = lds[base + t + 1];
#pragma unroll
            for (int j = 0; j < QT; j++) {
                float e0 = edot(c0, qx[j], qy[j], qz[j]);
                float e1 = edot(c1, qx[j], qy[j], qz[j]);
                gm[j] = fminf(fminf(e0, e1), gm[j]);
            }
        }
#pragma unroll
        for (int j = 0; j < QT; j++) {
            bool ok = gm[j] < bd[j];
            bd[j] = ok ? gm[j] : bd[j];
            gb[j] = ok ? g : gb[j];
        }
    }

    // epilogue: NO per-segment index recovery (deferred to finalize).
    // Rare too-close fallback rescans with the filter, resolves its exact
    // local index, and marks flag=1.
#pragma unroll
    for (int j = 0; j < QT; j++) {
        int loc = gb[j] << 4;            // group base (finalize scans 16)
        unsigned flag = 0u;
        float tmin = MIN_T2 - qc2[j];
        if (bd[j] < tmin) {
            float fb = __builtin_inff(); int fi = 0;
            for (int i = 0; i < segn; i++) {
                float4 c = lds[(i >> 4) * GSTRIDE + (i & (G - 1))];
                float e = edot(c, qx[j], qy[j], qz[j]);
                bool ok = (e >= tmin) && (e < fb);
                fb = ok ? e : fb;
                fi = ok ? i : fi;
            }
            bd[j] = fb; loc = fi; flag = 1u;
        }
        int q = b * MM + m0 + j * TPB;
        unsigned long long key =
            ((unsigned long long)emap(bd[j]) << 32) |
            ((unsigned)seg << 15) | ((unsigned)loc << 8) | (flag << 7);
        partials[(size_t)seg * NQ + q] = key;
    }
}

// Kernel 2: per-query u64-min (seg-split), then ONE deferred index
// recovery per query (R12-verified): decode (e, seg, loc, flag); if
// flag=0, equality-scan the winning group's 16 candidates recomputed from
// vt/valid via the SHARED helpers (bit-exact vs nn's scan). Pads: address
// clamped, e predicated to +inf. flag=1: loc is exact.
__global__ __launch_bounds__(128) void finalize_kernel(
    const unsigned long long* __restrict__ partials,
    const float* __restrict__ cloth, const float* __restrict__ vt,
    const int* __restrict__ valid,
    const int* __restrict__ smpl_idx, const float* __restrict__ sdf,
    const int* __restrict__ cloth_idx, const float* __restrict__ sdf_thresh,
    const float* __restrict__ dist_thresh,
    float* __restrict__ bsum, int* __restrict__ bmatch)
{
    int lq   = threadIdx.x & 63;
    int half = threadIdx.x >> 6;              // 0 or 1 (wave-uniform)
    int q = blockIdx.x * 64 + lq;             // 512 blocks x 64 queries
    int b = q >> 13;
    int s0 = half * 32;
    unsigned long long mm[8];
#pragma unroll
    for (int k = 0; k < 8; k++) mm[k] = ~0ULL;
#pragma unroll
    for (int s = 0; s < 32; s += 8) {
#pragma unroll
        for (int k = 0; k < 8; k++)
            mm[k] = u64min(mm[k], partials[(size_t)(s0 + s + k) * NQ + q]);
    }
    unsigned long long key =
        u64min(u64min(u64min(mm[0], mm[1]), u64min(mm[2], mm[3])),
               u64min(u64min(mm[4], mm[5]), u64min(mm[6], mm[7])));

    __shared__ unsigned long long lk[64];
    if (half == 1) lk[lq] = key;
    __syncthreads();
    if (half == 0) {
        key = u64min(key, lk[lq]);

        unsigned em = (unsigned)(key >> 32);
        unsigned lw = (unsigned)key;
        int seg  = (int)((lw >> 15) & 63u);
        int loc  = (int)((lw >> 8) & 127u);
        int flag = (int)((lw >> 7) & 1u);
        // inverse of emap
        unsigned tb2 = (em & 0x80000000u) ? (em ^ 0x80000000u) : ~em;
        float tgt = __uint_as_float(tb2);

        int n0   = seg * SEGN;
        int segn = (NN - n0 < SEGN) ? (NN - n0) : SEGN;
        int qm = q & (MM - 1);
        const float* qp = cloth + ((size_t)b * MM + qm) * 3;
        float qx = qp[0], qy = qp[1], qz = qp[2];
        float qc2 = qx * qx + qy * qy + qz * qz;
        const float* vtb    = vt + (size_t)b * NN * 3;
        const int*   validb = valid + b * NN;

        int tloc = 0;
        if (!flag) {
            // downward override -> lowest matching t; 16 independent
            // L2-resident gathers in flight (vt+valid ~440KB)
#pragma unroll
            for (int t = G - 1; t >= 0; --t) {
                int n  = n0 + loc + t;
                int nc = (n < NN) ? n : (NN - 1);      // safe address
                float4 c = prep_cand(vtb, validb, nc);
                float e = ((loc + t) < segn) ? edot(c, qx, qy, qz)
                                             : __builtin_inff();
                tloc = (e == tgt) ? t : tloc;
            }
        }
        int idx = n0 + loc + tloc;                     // flag=1 -> tloc=0

        float d2v = tgt + qc2;
        int target = smpl_idx[b * NN + idx];
        int ci0 = cloth_idx[0], ci1 = cloth_idx[1];
        bool match = (target == ci0) || (target == ci1);
        bool near_ = sqrtf(d2v) < dist_thresh[0];      // inf -> false
        float s = sdf[q];
        float contrib = near_ ? (match ? fabsf(s) : fabsf(s - sdf_thresh[0]))
                              : 0.0f;
        int mt = match ? 1 : 0;

        for (int off = 32; off > 0; off >>= 1) {
            contrib += __shfl_down(contrib, off, 64);
            mt      |= __shfl_down(mt, off, 64);
        }
        if (lq == 0) {
            bsum[blockIdx.x]   = contrib;
            bmatch[blockIdx.x] = mt;
        }
    }
}

// Kernel 3: 512 block-partials -> 4 batch losses. Wave w reduces partials
// [64w,64w+64) (all one batch); pairs of wave sums combine via LDS.
__global__ __launch_bounds__(512) void reduce_kernel(
    const float* __restrict__ bs, const int* __restrict__ bm,
    float* __restrict__ out)
{
    int t = threadIdx.x;          // 0..511
    float s = bs[t];
    int   m = bm[t];
    for (int off = 32; off > 0; off >>= 1) {
        s += __shfl_down(s, off, 64);
        m |= __shfl_down(m, off, 64);
    }
    __shared__ float wsu[8];
    __shared__ int   wma[8];
    int w = t >> 6;
    if ((t & 63) == 0) { wsu[w] = s; wma[w] = m; }
    __syncthreads();
    if (t < BB) {
        float sb = wsu[2 * t] + wsu[2 * t + 1];
        int   mb = wma[2 * t] | wma[2 * t + 1];
        out[t] = sb * (1.0f / (float)MM) * (mb ? 1.0f : 0.0f);
    }
}

extern "C" void kernel_launch(void* const* d_in, const int* in_sizes, int n_in,
                              void* d_out, int out_size, void* d_ws, size_t ws_size,
                              hipStream_t stream)
{
    const float* sdf         = (const float*)d_in[0];
    const float* cloth       = (const float*)d_in[1];
    const int*   smpl_idx    = (const int*)d_in[2];
    const int*   valid       = (const int*)d_in[3];
    const int*   cloth_idx   = (const int*)d_in[4];
    const float* sdf_thresh  = (const float*)d_in[5];
    const float* dist_thresh = (const float*)d_in[6];
    const float* vt          = (const float*)d_in[7];

    char* ws = (char*)d_ws;
    unsigned long long* partials = (unsigned long long*)ws;
    float* bsum   = (float*)(ws + OFF_BSUM);
    int*   bmatch = (int*)(ws + OFF_BMATCH);

    nn_kernel<<<BB * CHUNKS * NSEG, TPB, 0, stream>>>(cloth, vt, valid, partials);
    finalize_kernel<<<NFBLK, 128, 0, stream>>>(
        partials, cloth, vt, valid, smpl_idx, sdf, cloth_idx, sdf_thresh,
        dist_thresh, bsum, bmatch);
    reduce_kernel<<<1, 512, 0, stream>>>(bsum, bmatch, (float*)d_out);
}

// Round 14
// 99.762 us; speedup vs baseline: 1.0315x; 1.0315x over previous
//
#include <hip/hip_runtime.h>
#include <cstdint>
#include <cstddef>

// Problem constants (match reference file)
#define BB 4
#define MM 8192
#define NN 6890
#define NSEG 64
#define SEGN 108          // ceil(6890/64); last segment has 86
#define G 16              // tournament group size
#define GMAX 7            // max groups per segment
#define GSTRIDE 17        // group stride in float4 slots
#define CHUNKS 8          // MM / MQ
#define MQ 1024           // queries per nn block (TPB * QT)
#define QT 4              // queries per thread
#define TPB 256
#define NQ (BB * MM)      // 32768 queries
#define NFBLK 512         // finalize blocks (seg-split)

static constexpr float MIN_T2 = 0.005f * 0.005f;   // MIN_DIST_THRESH^2

// ws layout (bytes):
//   [0, 16777216)            u64 partials[NSEG][NQ]
//       key = emap(e)<<32 | seg<<15 | loc<<8 | flag<<7
//   [16777216, +2048)        float bsum[512]
//   [16779264, +2048)        int   bmatch[512]
#define OFF_BSUM   16777216
#define OFF_BMATCH (16777216 + 2048)

static __device__ __forceinline__ unsigned long long u64min(
    unsigned long long a, unsigned long long b) { return a < b ? a : b; }

// Shared helpers: IDENTICAL expressions in nn (scan) and finalize
// (recovery) so recomputed e is bit-exact.
static __device__ __forceinline__ float4 prep_cand(
    const float* __restrict__ vtb, const int* __restrict__ validb, int n)
{
    const float* p = vtb + (size_t)n * 3;
    float x = p[0], y = p[1], z = p[2];
    float s2 = x * x + y * y + z * z;
    if (validb[n] <= 0) s2 = __builtin_inff();
    return make_float4(-2.0f * x, -2.0f * y, -2.0f * z, s2);
}
static __device__ __forceinline__ float edot(float4 c, float qx, float qy,
                                             float qz)
{
    return fmaf(c.x, qx, fmaf(c.y, qy, fmaf(c.z, qz, c.w)));
}
// order-preserving float->u32 (monotone over all floats incl. negatives)
static __device__ __forceinline__ unsigned emap(float e) {
    unsigned b = __float_as_uint(e);
    return ((int)b < 0) ? ~b : (b | 0x80000000u);
}

// Kernel 1: per-(batch, m-chunk, n-segment) NN, group tournament,
// deferred index recovery. == EXACT R12 (best measured: 99.9us) ==
// R13 post-mortem: QT=8/CHUNKS=4 (halved waves -> halved LDS pipe load,
// halved TLP) REGRESSED +3us. With R9 (+TLP at doubled LDS load: -5us)
// this brackets nn as LATENCY-HIDING-BOUND: wave count > LDS-pipe slack.
// This config (8 waves/SIMD, QT=4, deferred recovery) is the measured
// optimum over NSEG{32,64,128} x QT{4,8} x TPB{256,512}. Allocator traps
// confirmed both directions (R6/R10: bounds-pinning or forced unroll ->
// scratch spill). DO NOT re-unroll, re-pin, or change wave geometry.
__global__ __launch_bounds__(TPB) void nn_kernel(
    const float* __restrict__ cloth, const float* __restrict__ vt,
    const int* __restrict__ valid, unsigned long long* __restrict__ partials)
{
    __shared__ float4 lds[GMAX * GSTRIDE];   // 119 float4 = 1904 B
    int bid   = blockIdx.x;            // 2048 blocks = 8/CU
    int seg   = bid & (NSEG - 1);
    int chunk = (bid >> 6) & (CHUNKS - 1);
    int b     = bid >> 9;
    int n0    = seg * SEGN;
    int segn  = (NN - n0 < SEGN) ? (NN - n0) : SEGN;
    int ngroups = (segn + G - 1) / G;
    int npad    = ngroups * G;

    const float* vtb    = vt + (size_t)b * NN * 3;
    const int*   validb = valid + b * NN;

    // fused candidate prep (shared helper); pads (0,0,0,+inf) inert
    if (threadIdx.x < npad) {
        float4 v = make_float4(0.0f, 0.0f, 0.0f, __builtin_inff());
        if (threadIdx.x < segn) v = prep_cand(vtb, validb, n0 + threadIdx.x);
        int slot = (threadIdx.x >> 4) * GSTRIDE + (threadIdx.x & (G - 1));
        lds[slot] = v;
    }

    float qx[QT], qy[QT], qz[QT], qc2[QT], bd[QT];
    int gb[QT];
    int m0 = chunk * MQ + threadIdx.x;
#pragma unroll
    for (int j = 0; j < QT; j++) {
        int m = m0 + j * TPB;
        const float* p = cloth + ((size_t)b * MM + m) * 3;
        float x = p[0], y = p[1], z = p[2];
        qx[j] = x; qy[j] = y; qz[j] = z;
        qc2[j] = x * x + y * y + z * z;
        bd[j] = __builtin_inff();
        gb[j] = 0;
    }
    __syncthreads();

    // Hot loop: UNFILTERED value-min in shifted space e = s2 - 2 c.s,
    // group tournament, candidates in pairs -> min3 fold.
    for (int g = 0; g < ngroups; g++) {
        int base = g * GSTRIDE;
        float gm[QT];
#pragma unroll
        for (int j = 0; j < QT; j++) gm[j] = __builtin_inff();
#pragma unroll
        for (int t = 0; t < G; t += 2) {
            float4 c0 = lds[base + t];
            float4 c1 = lds[base + t + 1];
#pragma unroll
            for (int j = 0; j < QT; j++) {
                float e0 = edot(c0, qx[j], qy[j], qz[j]);
                float e1 = edot(c1, qx[j], qy[j], qz[j]);
                gm[j] = fminf(fminf(e0, e1), gm[j]);
            }
        }
#pragma unroll
        for (int j = 0; j < QT; j++) {
            bool ok = gm[j] < bd[j];
            bd[j] = ok ? gm[j] : bd[j];
            gb[j] = ok ? g : gb[j];
        }
    }

    // epilogue: NO per-segment index recovery (deferred to finalize).
    // Rare too-close fallback rescans with the filter, resolves its exact
    // local index, and marks flag=1.
#pragma unroll
    for (int j = 0; j < QT; j++) {
        int loc = gb[j] << 4;            // group base (finalize scans 16)
        unsigned flag = 0u;
        float tmin = MIN_T2 - qc2[j];
        if (bd[j] < tmin) {
            float fb = __builtin_inff(); int fi = 0;
            for (int i = 0; i < segn; i++) {
                float4 c = lds[(i >> 4) * GSTRIDE + (i & (G - 1))];
                float e = edot(c, qx[j], qy[j], qz[j]);
                bool ok = (e >= tmin) && (e < fb);
                fb = ok ? e : fb;
                fi = ok ? i : fi;
            }
            bd[j] = fb; loc = fi; flag = 1u;
        }
        int q = b * MM + m0 + j * TPB;
        unsigned long long key =
            ((unsigned long long)emap(bd[j]) << 32) |
            ((unsigned)seg << 15) | ((unsigned)loc << 8) | (flag << 7);
        partials[(size_t)seg * NQ + q] = key;
    }
}

// Kernel 2: per-query u64-min (seg-split), then ONE deferred index
// recovery per query (R12-verified): decode (e, seg, loc, flag); if
// flag=0, equality-scan the winning group's 16 candidates recomputed from
// vt/valid via the SHARED helpers (bit-exact vs nn's scan). Pads: address
// clamped, e predicated to +inf. flag=1: loc is exact.
__global__ __launch_bounds__(128) void finalize_kernel(
    const unsigned long long* __restrict__ partials,
    const float* __restrict__ cloth, const float* __restrict__ vt,
    const int* __restrict__ valid,
    const int* __restrict__ smpl_idx, const float* __restrict__ sdf,
    const int* __restrict__ cloth_idx, const float* __restrict__ sdf_thresh,
    const float* __restrict__ dist_thresh,
    float* __restrict__ bsum, int* __restrict__ bmatch)
{
    int lq   = threadIdx.x & 63;
    int half = threadIdx.x >> 6;              // 0 or 1 (wave-uniform)
    int q = blockIdx.x * 64 + lq;             // 512 blocks x 64 queries
    int b = q >> 13;
    int s0 = half * 32;
    unsigned long long mm[8];
#pragma unroll
    for (int k = 0; k < 8; k++) mm[k] = ~0ULL;
#pragma unroll
    for (int s = 0; s < 32; s += 8) {
#pragma unroll
        for (int k = 0; k < 8; k++)
            mm[k] = u64min(mm[k], partials[(size_t)(s0 + s + k) * NQ + q]);
    }
    unsigned long long key =
        u64min(u64min(u64min(mm[0], mm[1]), u64min(mm[2], mm[3])),
               u64min(u64min(mm[4], mm[5]), u64min(mm[6], mm[7])));

    __shared__ unsigned long long lk[64];
    if (half == 1) lk[lq] = key;
    __syncthreads();
    if (half == 0) {
        key = u64min(key, lk[lq]);

        unsigned em = (unsigned)(key >> 32);
        unsigned lw = (unsigned)key;
        int seg  = (int)((lw >> 15) & 63u);
        int loc  = (int)((lw >> 8) & 127u);
        int flag = (int)((lw >> 7) & 1u);
        // inverse of emap
        unsigned tb2 = (em & 0x80000000u) ? (em ^ 0x80000000u) : ~em;
        float tgt = __uint_as_float(tb2);

        int n0   = seg * SEGN;
        int segn = (NN - n0 < SEGN) ? (NN - n0) : SEGN;
        int qm = q & (MM - 1);
        const float* qp = cloth + ((size_t)b * MM + qm) * 3;
        float qx = qp[0], qy = qp[1], qz = qp[2];
        float qc2 = qx * qx + qy * qy + qz * qz;
        const float* vtb    = vt + (size_t)b * NN * 3;
        const int*   validb = valid + b * NN;

        int tloc = 0;
        if (!flag) {
            // downward override -> lowest matching t; 16 independent
            // L2-resident gathers in flight (vt+valid ~440KB)
#pragma unroll
            for (int t = G - 1; t >= 0; --t) {
                int n  = n0 + loc + t;
                int nc = (n < NN) ? n : (NN - 1);      // safe address
                float4 c = prep_cand(vtb, validb, nc);
                float e = ((loc + t) < segn) ? edot(c, qx, qy, qz)
                                             : __builtin_inff();
                tloc = (e == tgt) ? t : tloc;
            }
        }
        int idx = n0 + loc + tloc;                     // flag=1 -> tloc=0

        float d2v = tgt + qc2;
        int target = smpl_idx[b * NN + idx];
        int ci0 = cloth_idx[0], ci1 = cloth_idx[1];
        bool match = (target == ci0) || (target == ci1);
        bool near_ = sqrtf(d2v) < dist_thresh[0];      // inf -> false
        float s = sdf[q];
        float contrib = near_ ? (match ? fabsf(s) : fabsf(s - sdf_thresh[0]))
                              : 0.0f;
        int mt = match ? 1 : 0;

        for (int off = 32; off > 0; off >>= 1) {
            contrib += __shfl_down(contrib, off, 64);
            mt      |= __shfl_down(mt, off, 64);
        }
        if (lq == 0) {
            bsum[blockIdx.x]   = contrib;
            bmatch[blockIdx.x] = mt;
        }
    }
}

// Kernel 3: 512 block-partials -> 4 batch losses. Wave w reduces partials
// [64w,64w+64) (all one batch); pairs of wave sums combine via LDS.
__global__ __launch_bounds__(512) void reduce_kernel(
    const float* __restrict__ bs, const int* __restrict__ bm,
    float* __restrict__ out)
{
    int t = threadIdx.x;          // 0..511
    float s = bs[t];
    int   m = bm[t];
    for (int off = 32; off > 0; off >>= 1) {
        s += __shfl_down(s, off, 64);
        m |= __shfl_down(m, off, 64);
    }
    __shared__ float wsu[8];
    __shared__ int   wma[8];
    int w = t >> 6;
    if ((t & 63) == 0) { wsu[w] = s; wma[w] = m; }
    __syncthreads();
    if (t < BB) {
        float sb = wsu[2 * t] + wsu[2 * t + 1];
        int   mb = wma[2 * t] | wma[2 * t + 1];
        out[t] = sb * (1.0f / (float)MM) * (mb ? 1.0f : 0.0f);
    }
}

extern "C" void kernel_launch(void* const* d_in, const int* in_sizes, int n_in,
                              void* d_out, int out_size, void* d_ws, size_t ws_size,
                              hipStream_t stream)
{
    const float* sdf         = (const float*)d_in[0];
    const float* cloth       = (const float*)d_in[1];
    const int*   smpl_idx    = (const int*)d_in[2];
    const int*   valid       = (const int*)d_in[3];
    const int*   cloth_idx   = (const int*)d_in[4];
    const float* sdf_thresh  = (const float*)d_in[5];
    const float* dist_thresh = (const float*)d_in[6];
    const float* vt          = (const float*)d_in[7];

    char* ws = (char*)d_ws;
    unsigned long long* partials = (unsigned long long*)ws;
    float* bsum   = (float*)(ws + OFF_BSUM);
    int*   bmatch = (int*)(ws + OFF_BMATCH);

    nn_kernel<<<BB * CHUNKS * NSEG, TPB, 0, stream>>>(cloth, vt, valid, partials);
    finalize_kernel<<<NFBLK, 128, 0, stream>>>(
        partials, cloth, vt, valid, smpl_idx, sdf, cloth_idx, sdf_thresh,
        dist_thresh, bsum, bmatch);
    reduce_kernel<<<1, 512, 0, stream>>>(bsum, bmatch, (float*)d_out);
}